// Round 4
// baseline (331.599 us; speedup 1.0000x reference)
//
#include <hip/hip_runtime.h>
#include <hip/hip_bf16.h>

// Problem constants (from reference)
#define N_NODES   40000
#define N_EDGES   640000
#define F         128      // F_IN == HID == 128
#define N_GRAPHS  64
#define N_CLASSES 10

typedef short bf16x8 __attribute__((ext_vector_type(8)));
typedef float f32x4  __attribute__((ext_vector_type(4)));
typedef unsigned int u32x4 __attribute__((ext_vector_type(4)));   // clang-native, for nontemporal builtins

// fp32 -> bf16 with round-to-nearest-even
__device__ __forceinline__ unsigned short f2bf(float f) {
    union { float f; unsigned u; } v; v.f = f;
    unsigned r = v.u + 0x7fffu + ((v.u >> 16) & 1u);
    return (unsigned short)(r >> 16);
}
__device__ __forceinline__ float bflo(unsigned u) { return __uint_as_float(u << 16); }
__device__ __forceinline__ float bfhi(unsigned u) { return __uint_as_float(u & 0xffff0000u); }
__device__ __forceinline__ unsigned pack2(float a, float b) {
    return (unsigned)f2bf(a) | ((unsigned)f2bf(b) << 16);
}

#define APITCH 136   // bf16 units; 272 B rows: 16B-aligned frags, bank-spread

// H / AGG live as TWO column panels [2][N][64] bf16 (5.12 MB each) so each
// gather pass's random-read working set fits (mostly) in a 4 MiB per-XCD L2.
#define PANEL_U4  ((size_t)N_NODES * 8)     // panel stride in uint4 units

// ---------------------------------------------------------------------------
// Precompute transposed bf16 weights: Wt_l[c][k] = bf16(W_l[k][c]), l=0..2.
// Fused: zero deg (for gemm1's degree count) and the scan ticket.
__global__ void wcvt_kernel(const float* __restrict__ W1, const float* __restrict__ W2,
                            const float* __restrict__ W3, unsigned short* __restrict__ Wt,
                            int* __restrict__ deg, int* __restrict__ tks) {
    int idx = blockIdx.x * 256 + threadIdx.x;          // 0 .. 3*16384-1
    if (idx < N_NODES) deg[idx] = 0;
    if (idx < 2) tks[idx] = 0;
    int l = idx >> 14;
    int r = idx & 16383;
    int c = r >> 7, k = r & 127;
    const float* W = (l == 0) ? W1 : ((l == 1) ? W2 : W3);
    Wt[idx] = f2bf(W[k * 128 + c]);                    // write coalesced (k fast)
}

// ---------------------------------------------------------------------------
// CSR scan v4 (validated R2): 40 blocks x 1000 nodes. Per-block sum ->
// chunkSum -> ticket spin -> wave-parallel scan of chunkSums. Also zeros
// pooled/cnt and computes dis[v] = rsqrt(deg[v]+1).
#define SCAN_BLOCKS 40
#define SCAN_CHUNK  1000
__global__ __launch_bounds__(256) void scan_kernel(
    const int* __restrict__ deg, int* __restrict__ rowptr,
    int* __restrict__ cursor, float* __restrict__ dis,
    float* __restrict__ pooled_zero, int* __restrict__ chunkSum,
    int* __restrict__ ticket) {
    __shared__ int wpart[4];
    __shared__ int blockBase;
    const int tid  = threadIdx.x;
    const int lane = tid & 63;
    const int wave = tid >> 6;
    const int b    = blockIdx.x;
    const int base = b * SCAN_CHUNK;

    for (int k = b * 256 + tid; k < N_GRAPHS * F + N_GRAPHS; k += SCAN_BLOCKS * 256)
        pooled_zero[k] = 0.f;

    int4 d = make_int4(0, 0, 0, 0);
    if (tid < 250) d = *(const int4*)(deg + base + tid * 4);
    const int sown = d.x + d.y + d.z + d.w;

    int s = sown;
#pragma unroll
    for (int off = 1; off < 64; off <<= 1) {
        int n = __shfl_up(s, off, 64);
        if (lane >= off) s += n;
    }
    if (lane == 63) wpart[wave] = s;
    __syncthreads();

    if (tid == 0) {
        int run = 0;
#pragma unroll
        for (int w = 0; w < 4; ++w) { int t = wpart[w]; wpart[w] = run; run += t; }
        atomicExch(&chunkSum[b], run);
        __threadfence();
        atomicAdd(ticket, 1);
        while (atomicAdd(ticket, 0) < SCAN_BLOCKS) { }
    }
    __syncthreads();

    // Wave 0: parallel exclusive scan of chunkSum[0..39] (atomic loads for
    // cross-XCD visibility; one round-trip instead of b serial ones).
    if (wave == 0) {
        int cs = (lane < SCAN_BLOCKS) ? atomicAdd(&chunkSum[lane], 0) : 0;
        int sc_ = cs;
#pragma unroll
        for (int off = 1; off < 64; off <<= 1) {
            int n = __shfl_up(sc_, off, 64);
            if (lane >= off) sc_ += n;
        }
        int bb = __shfl(sc_, (b == 0) ? 0 : b - 1, 64);
        if (lane == 0) blockBase = (b == 0) ? 0 : bb;
    }
    __syncthreads();

    if (tid < 250) {
        int excl = blockBase + wpart[wave] + (s - sown);
        int4 r;
        r.x = excl;
        r.y = r.x + d.x;
        r.z = r.y + d.y;
        r.w = r.z + d.z;
        *(int4*)(rowptr + base + tid * 4) = r;
        *(int4*)(cursor + base + tid * 4) = r;
        float4 di;
        di.x = rsqrtf((float)d.x + 1.0f);
        di.y = rsqrtf((float)d.y + 1.0f);
        di.z = rsqrtf((float)d.z + 1.0f);
        di.w = rsqrtf((float)d.w + 1.0f);
        *(float4*)(dis + base + tid * 4) = di;
    }
}

// CSR build step 3: csr_src[cursor[col[e]]++] = row[e]
__global__ void fill_kernel(const int* __restrict__ row, const int* __restrict__ col,
                            int* __restrict__ cursor, int* __restrict__ csr_src) {
    int e = blockIdx.x * 256 + threadIdx.x;
    if (e < N_EDGES) {
        int pos = atomicAdd(&cursor[col[e]], 1);
        csr_src[pos] = row[e];
    }
}

// ---------------------------------------------------------------------------
// MFMA GEMM v3: Hb[r][c] = bf16( scale_r * relu?(A[r][:] + bias) @ W )
// A (bf16 case) read from panel layout [2][N][64]; D written to panel layout.
// W^T staged in TWO 64-col halves: LDS = As 17KB + Ws-half 17KB = 34 KB.
// Fragment maps (verified m89/m92/m120): A: m=lane&15, k=quad*8+j;
// B^T: n=lane&15, k=quad*8+j; D: col=lane&15, row=quad*4+reg.
template<bool ABF16, bool RELU, bool SCALE, bool COUNT>
__global__ __launch_bounds__(256) void gemm_mfma(
    const void* __restrict__ Araw, const unsigned short* __restrict__ Wt,
    const float* __restrict__ bias, const float* __restrict__ dis,
    unsigned short* __restrict__ Hb,
    const int* __restrict__ cnt_col, int* __restrict__ cnt_deg) {
    __shared__ unsigned short As[64 * APITCH];    // 17408 B
    __shared__ unsigned short Ws[64 * APITCH];    // 17408 B (one 64-col half)
    const int tid  = threadIdx.x;
    const int row0 = blockIdx.x * 64;

    if (COUNT) {   // fused degree count for CSR build (deg pre-zeroed)
        int t = (blockIdx.x * 256 + tid) * 4;
#pragma unroll
        for (int j = 0; j < 4; ++j) atomicAdd(&cnt_deg[cnt_col[t + j]], 1);
    }

    // Stage Ws half 0 (cols 0..63 of W^T; 1024 uint4)
    {
        const uint4* src = (const uint4*)Wt;
#pragma unroll
        for (int j = 0; j < 4; ++j) {
            int c4 = tid + j * 256;        // 0..1023; 16 uint4 per 128-bf16 row
            int c  = c4 >> 4;
            int o  = c4 & 15;
            *(uint4*)(Ws + c * APITCH + o * 8) = src[c4];
        }
    }
    // Stage A -> bias/relu -> bf16 -> As
    if (ABF16) {
        const uint4* src = (const uint4*)Araw;     // panel layout [2][N][64]
#pragma unroll
        for (int j = 0; j < 4; ++j) {
            int c4 = tid + j * 256;        // 0..1023
            int r  = c4 >> 4;
            int p  = c4 & 15;
            int o  = p << 3;               // bf16 col offset (8 per chunk)
            uint4 hv = src[(size_t)(p >> 3) * PANEL_U4 + (size_t)(row0 + r) * 8 + (p & 7)];
            float f0 = bflo(hv.x), f1 = bfhi(hv.x), f2 = bflo(hv.y), f3 = bfhi(hv.y);
            float f4_ = bflo(hv.z), f5 = bfhi(hv.z), f6 = bflo(hv.w), f7 = bfhi(hv.w);
            if (bias) {
                float4 b0 = *(const float4*)(bias + o);
                float4 b1 = *(const float4*)(bias + o + 4);
                f0 += b0.x; f1 += b0.y; f2 += b0.z; f3 += b0.w;
                f4_ += b1.x; f5 += b1.y; f6 += b1.z; f7 += b1.w;
            }
            if (RELU) {
                f0 = fmaxf(f0, 0.f); f1 = fmaxf(f1, 0.f); f2 = fmaxf(f2, 0.f);
                f3 = fmaxf(f3, 0.f); f4_ = fmaxf(f4_, 0.f); f5 = fmaxf(f5, 0.f);
                f6 = fmaxf(f6, 0.f); f7 = fmaxf(f7, 0.f);
            }
            uint4 pk;
            pk.x = pack2(f0, f1); pk.y = pack2(f2, f3);
            pk.z = pack2(f4_, f5); pk.w = pack2(f6, f7);
            *(uint4*)(As + r * APITCH + o) = pk;
        }
    } else {
        const float* A = (const float*)Araw;   // x: row-major [N][128] fp32
#pragma unroll
        for (int j = 0; j < 8; ++j) {
            int c4 = tid + j * 256;            // 0..2047; 32 float4 per row
            int r  = c4 >> 5;
            int o  = (c4 & 31) << 2;
            float4 v = *(const float4*)(A + (size_t)(row0 + r) * F + o);
            if (bias) {
                v.x += bias[o + 0]; v.y += bias[o + 1];
                v.z += bias[o + 2]; v.w += bias[o + 3];
            }
            if (RELU) {
                v.x = fmaxf(v.x, 0.f); v.y = fmaxf(v.y, 0.f);
                v.z = fmaxf(v.z, 0.f); v.w = fmaxf(v.w, 0.f);
            }
            uint2 p;
            p.x = pack2(v.x, v.y);
            p.y = pack2(v.z, v.w);
            *(uint2*)(As + r * APITCH + o) = p;
        }
    }
    __syncthreads();

    const int lane = tid & 63;
    const int wave = tid >> 6;
    const int m16  = lane & 15;
    const int quad = lane >> 4;

    f32x4 acc[8];
#pragma unroll
    for (int t = 0; t < 8; ++t) acc[t] = (f32x4)(0.0f);

    // A fragments are reused across both halves — load once.
    bf16x8 afrag[4];
#pragma unroll
    for (int kk = 0; kk < 4; ++kk)
        afrag[kk] = *(const bf16x8*)(As + (wave * 16 + m16) * APITCH + kk * 32 + quad * 8);

    // --- half 0: output cols 0..63 (acc[0..3]) ---
#pragma unroll
    for (int kk = 0; kk < 4; ++kk) {
#pragma unroll
        for (int t = 0; t < 4; ++t) {
            bf16x8 b = *(const bf16x8*)(Ws + (t * 16 + m16) * APITCH + kk * 32 + quad * 8);
            acc[t] = __builtin_amdgcn_mfma_f32_16x16x32_bf16(afrag[kk], b, acc[t], 0, 0, 0);
        }
    }
    __syncthreads();   // all waves done reading Ws half 0

    // Stage Ws half 1 (cols 64..127)
    {
        const uint4* src = (const uint4*)Wt + 1024;
#pragma unroll
        for (int j = 0; j < 4; ++j) {
            int c4 = tid + j * 256;
            int c  = c4 >> 4;
            int o  = c4 & 15;
            *(uint4*)(Ws + c * APITCH + o * 8) = src[c4];
        }
    }
    __syncthreads();

    // --- half 1: output cols 64..127 (acc[4..7]) ---
#pragma unroll
    for (int kk = 0; kk < 4; ++kk) {
#pragma unroll
        for (int t = 0; t < 4; ++t) {
            bf16x8 b = *(const bf16x8*)(Ws + (t * 16 + m16) * APITCH + kk * 32 + quad * 8);
            acc[4 + t] = __builtin_amdgcn_mfma_f32_16x16x32_bf16(afrag[kk], b, acc[4 + t], 0, 0, 0);
        }
    }

    // Epilogue: D row = quad*4+reg, col = t*16+m16; optional dis[row] scale.
    // Stage into As rows (wave-private) -> read back -> coalesced panel stores.
    const int rloc = wave * 16 + quad * 4;
    float sc[4];
#pragma unroll
    for (int rg = 0; rg < 4; ++rg) sc[rg] = SCALE ? dis[row0 + rloc + rg] : 1.0f;
#pragma unroll
    for (int t = 0; t < 8; ++t) {
        int col = t * 16 + m16;
#pragma unroll
        for (int rg = 0; rg < 4; ++rg)
            As[(rloc + rg) * APITCH + col] = f2bf(acc[t][rg] * sc[rg]);
    }
#pragma unroll
    for (int i = 0; i < 4; ++i) {
        int idx = lane + i * 64;          // 0..255
        int r   = idx >> 4;               // 0..15
        int p   = idx & 15;               // 16B chunk; panel = p>>3
        uint4 val = *(const uint4*)(As + (wave * 16 + r) * APITCH + p * 8);
        *((uint4*)Hb + (size_t)(p >> 3) * PANEL_U4
                     + (size_t)(row0 + wave * 16 + r) * 8 + (p & 7)) = val;
    }
}

// ---------------------------------------------------------------------------
// Gather aggregation v7 (panel-split): one wave per node per PANEL PASS.
// Grid = 20000 blocks: blocks [0,10000) aggregate panel 0, [10000,20000)
// panel 1 — dispatch-order phase separation keeps the random-read working
// set at ~5.6 MB (panel 5.12 MB + csr) so most gathers hit per-XCD L2
// instead of L3.  Octet layout: 8 lanes x 16B cover one 128B half-row; 4
// independent uint4 gathers in flight per lane (32 edges/step) — same
// VGPR class and fma/byte as v5 (v6 lesson: don't trade occupancy for ILP).
// csr reads nontemporal (streaming); AGG writes nontemporal (consumed next
// kernel) so they don't evict the hot panel from L2.
// SCALED=false: Hb pre-scaled by dis[row]:  AGG[v] = dis[v]*(sum Hb[src] + Hb[v])
// SCALED=true : AGG[v] = dis[v]*(sum dis[src]*Hb[src] + dis[v]*Hb[v])
template <bool SCALED>
__global__ __launch_bounds__(256) void gather_kernel(
    const unsigned short* __restrict__ Hb, const int* __restrict__ csr_src,
    const int* __restrict__ rowptr, const int* __restrict__ deg,
    const float* __restrict__ dis, unsigned short* __restrict__ AGGb) {
    const int pass = (blockIdx.x >= 10000) ? 1 : 0;
    const int b    = blockIdx.x - pass * 10000;
    const int v    = b * 4 + (threadIdx.x >> 6);
    const int lane = threadIdx.x & 63;
    const int c8   = lane & 7;           // 16B chunk of the 128B half-row
    const int oct  = lane >> 3;          // edge slot within group of 8

    const int start = rowptr[v];
    const int len   = deg[v];
    const uint4* Hp = (const uint4*)Hb + (size_t)pass * PANEL_U4 + c8;

    float acc[8];
#pragma unroll
    for (int i = 0; i < 8; ++i) acc[i] = 0.f;

    for (int j0 = 0; j0 < len; j0 += 64) {
        int m = len - j0; if (m > 64) m = 64;
        int nidx = (lane < m) ? __builtin_nontemporal_load(csr_src + start + j0 + lane) : 0;
        for (int j = 0; j < m; j += 32) {
            int   r[4];
            float w[4];
            uint4 h[4];
#pragma unroll
            for (int u = 0; u < 4; ++u) {
                int  sl    = j + u * 8 + oct;
                bool valid = sl < m;
                r[u] = __shfl(nidx, valid ? sl : 0, 64);
                w[u] = valid ? (SCALED ? dis[r[u]] : 1.0f) : 0.0f;
            }
#pragma unroll
            for (int u = 0; u < 4; ++u) h[u] = Hp[(size_t)r[u] * 8];
#pragma unroll
            for (int u = 0; u < 4; ++u) {
                acc[0] = fmaf(bflo(h[u].x), w[u], acc[0]);
                acc[1] = fmaf(bfhi(h[u].x), w[u], acc[1]);
                acc[2] = fmaf(bflo(h[u].y), w[u], acc[2]);
                acc[3] = fmaf(bfhi(h[u].y), w[u], acc[3]);
                acc[4] = fmaf(bflo(h[u].z), w[u], acc[4]);
                acc[5] = fmaf(bfhi(h[u].z), w[u], acc[5]);
                acc[6] = fmaf(bflo(h[u].w), w[u], acc[6]);
                acc[7] = fmaf(bfhi(h[u].w), w[u], acc[7]);
            }
        }
    }

    // Reduce across the 8 octets (lanes with equal lane&7 hold partials).
#pragma unroll
    for (int i = 0; i < 8; ++i) {
        acc[i] += __shfl_xor(acc[i], 8, 64);
        acc[i] += __shfl_xor(acc[i], 16, 64);
        acc[i] += __shfl_xor(acc[i], 32, 64);
    }

    if (oct == 0) {       // lanes 0..7 = the 8 chunks of the 128B half-row
        float dc  = dis[v];
        float ws_ = SCALED ? dc : 1.0f;
        uint4 h = Hp[(size_t)v * 8];               // self-loop
        acc[0] = fmaf(bflo(h.x), ws_, acc[0]); acc[1] = fmaf(bfhi(h.x), ws_, acc[1]);
        acc[2] = fmaf(bflo(h.y), ws_, acc[2]); acc[3] = fmaf(bfhi(h.y), ws_, acc[3]);
        acc[4] = fmaf(bflo(h.z), ws_, acc[4]); acc[5] = fmaf(bfhi(h.z), ws_, acc[5]);
        acc[6] = fmaf(bflo(h.w), ws_, acc[6]); acc[7] = fmaf(bfhi(h.w), ws_, acc[7]);
        u32x4 pk;
        pk.x = pack2(acc[0] * dc, acc[1] * dc);
        pk.y = pack2(acc[2] * dc, acc[3] * dc);
        pk.z = pack2(acc[4] * dc, acc[5] * dc);
        pk.w = pack2(acc[6] * dc, acc[7] * dc);
        u32x4* dst = (u32x4*)((uint4*)AGGb + (size_t)pass * PANEL_U4 + (size_t)v * 8 + c8);
        __builtin_nontemporal_store(pk, dst);
    }
}

// ---------------------------------------------------------------------------
// Pool v4: panel-layout reads; 400 blocks x 100 nodes; 8 row-slots x 32
// lanes x 4 cols. pooled[g][f] += relu(AGG[v][f] + b3[f]); cnt[g] += 1.
// batch sorted -> per-slot run-length accumulate, flush on change.
#define POOL_NODES 100
__global__ __launch_bounds__(256) void pool_kernel(
    const unsigned short* __restrict__ AGGb, const int* __restrict__ batch,
    const float* __restrict__ b3,
    float* __restrict__ pooled, float* __restrict__ cnt) {
    const int tid  = threadIdx.x;
    const int f4   = (tid & 31) << 2;     // 4-col group (0..124)
    const int slot = tid >> 5;            // 0..7
    const int base = blockIdx.x * POOL_NODES;
    const float4 bf = *(const float4*)(b3 + f4);
    const unsigned short* Ap = AGGb + (size_t)(f4 >> 6) * N_NODES * 64 + (f4 & 63);

    float4 acc = make_float4(0.f, 0.f, 0.f, 0.f);
    float c = 0.f;
    int gcur = -1;
    for (int j = slot; j < POOL_NODES; j += 8) {
        int v = base + j;                 // 400*100 = 40000, always in range
        int g = batch[v];
        if (g != gcur) {
            if (gcur >= 0) {
                float* dst = pooled + gcur * F + f4;
                atomicAdd(dst + 0, acc.x); atomicAdd(dst + 1, acc.y);
                atomicAdd(dst + 2, acc.z); atomicAdd(dst + 3, acc.w);
                if (f4 == 0) atomicAdd(&cnt[gcur], c);
            }
            acc = make_float4(0.f, 0.f, 0.f, 0.f); c = 0.f; gcur = g;
        }
        uint2 a = *(const uint2*)(Ap + (size_t)v * 64);
        acc.x += fmaxf(bflo(a.x) + bf.x, 0.f);
        acc.y += fmaxf(bfhi(a.x) + bf.y, 0.f);
        acc.z += fmaxf(bflo(a.y) + bf.z, 0.f);
        acc.w += fmaxf(bfhi(a.y) + bf.w, 0.f);
        c += 1.f;
    }
    if (gcur >= 0) {
        float* dst = pooled + gcur * F + f4;
        atomicAdd(dst + 0, acc.x); atomicAdd(dst + 1, acc.y);
        atomicAdd(dst + 2, acc.z); atomicAdd(dst + 3, acc.w);
        if (f4 == 0) atomicAdd(&cnt[gcur], c);
    }
}

// ---------------------------------------------------------------------------
// Head: out[g][c] = (sum_f pooled[g][f] * Wl[f][c]) / max(cnt[g],1) + bl[c]
__global__ void head_kernel(const float* __restrict__ pooled,
                            const float* __restrict__ cnt,
                            const float* __restrict__ Wl,
                            const float* __restrict__ bl,
                            float* __restrict__ out) {
    int tid = threadIdx.x;
    if (tid >= N_GRAPHS * N_CLASSES) return;
    int g = tid / N_CLASSES, c = tid % N_CLASSES;
    float acc = 0.f;
    for (int ff = 0; ff < F; ++ff)
        acc += pooled[g * F + ff] * Wl[ff * N_CLASSES + c];
    out[g * N_CLASSES + c] = acc / fmaxf(cnt[g], 1.f) + bl[c];
}

// ---------------------------------------------------------------------------
extern "C" void kernel_launch(void* const* d_in, const int* in_sizes, int n_in,
                              void* d_out, int out_size, void* d_ws, size_t ws_size,
                              hipStream_t stream) {
    const float* x    = (const float*)d_in[0];
    const int*   ei   = (const int*)d_in[1];     // [2][E]
    const int*   bat  = (const int*)d_in[2];
    const float* W1   = (const float*)d_in[3];
    const float* b1   = (const float*)d_in[4];
    const float* W2   = (const float*)d_in[5];
    const float* b2   = (const float*)d_in[6];
    const float* W3   = (const float*)d_in[7];
    const float* b3   = (const float*)d_in[8];
    const float* Wl   = (const float*)d_in[9];
    const float* bl   = (const float*)d_in[10];
    float* out = (float*)d_out;

    const int* row = ei;                 // edge_index[0] (source)
    const int* col = ei + N_EDGES;       // edge_index[1] (target)

    // Workspace layout (16B-aligned chunks)
    float*          ws      = (float*)d_ws;
    float*          dis     = ws;                                     // 40000 f
    unsigned short* Hb      = (unsigned short*)(dis + N_NODES);       // 5.12M bf16 (2 panels)
    unsigned short* AGGb    = Hb + (size_t)N_NODES * F;               // 5.12M bf16 (2 panels)
    float*          pooled  = (float*)(AGGb + (size_t)N_NODES * F);   // 8192 f
    float*          cnt     = pooled + N_GRAPHS * F;                  // 64 f
    int*            deg     = (int*)(cnt + N_GRAPHS);                 // 40000 i
    int*            rowptr  = deg + N_NODES;                          // 40000 i
    int*            cursor  = rowptr + N_NODES;                       // 40000 i
    int*            csr_src = cursor + N_NODES;                       // 640000 i
    unsigned short* Wtb     = (unsigned short*)(csr_src + N_EDGES);   // 3*16384 bf16
    int*            chunkSum= (int*)(Wtb + 3 * 16384);                // 40 i
    int*            tks     = chunkSum + SCAN_BLOCKS;                 // 2 i

    const int edgeGrid   = (N_EDGES + 255) / 256;      // 2500
    const int gemmGrid   = N_NODES / 64;               // 625
    const int gatherGrid = 20000;                      // 2 panel passes x 10000

    // --- W convert + zero deg/ticket (one kernel) ---
    wcvt_kernel<<<192, 256, 0, stream>>>(W1, W2, W3, Wtb, deg, tks);

    // --- layer 1 GEMM (unscaled bf16 H, fused degree count), then CSR build ---
    gemm_mfma<false, false, false, true><<<gemmGrid, 256, 0, stream>>>(
        x, Wtb, nullptr, nullptr, Hb, col, deg);
    scan_kernel<<<SCAN_BLOCKS, 256, 0, stream>>>(deg, rowptr, cursor, dis,
                                                 pooled, chunkSum, &tks[0]);
    fill_kernel<<<edgeGrid, 256, 0, stream>>>(row, col, cursor, csr_src);
    gather_kernel<true><<<gatherGrid, 256, 0, stream>>>(Hb, csr_src, rowptr, deg, dis, AGGb);

    // --- layer 2 (relu(agg+b1) fused into staging; H pre-scaled by dis) ---
    gemm_mfma<true, true, true, false><<<gemmGrid, 256, 0, stream>>>(
        AGGb, Wtb + 16384, b1, dis, Hb, nullptr, nullptr);
    gather_kernel<false><<<gatherGrid, 256, 0, stream>>>(Hb, csr_src, rowptr, deg, dis, AGGb);

    // --- layer 3 ---
    gemm_mfma<true, true, true, false><<<gemmGrid, 256, 0, stream>>>(
        AGGb, Wtb + 32768, b2, dis, Hb, nullptr, nullptr);
    gather_kernel<false><<<gatherGrid, 256, 0, stream>>>(Hb, csr_src, rowptr, deg, dis, AGGb);

    // --- pool (fuses relu(agg + b3)) + head ---
    pool_kernel<<<N_NODES / POOL_NODES, 256, 0, stream>>>(AGGb, bat, b3, pooled, cnt);
    head_kernel<<<1, N_GRAPHS * N_CLASSES, 0, stream>>>(pooled, cnt, Wl, bl, out);
}

// Round 5
// 292.984 us; speedup vs baseline: 1.1318x; 1.1318x over previous
//
#include <hip/hip_runtime.h>
#include <hip/hip_bf16.h>

// Problem constants (from reference)
#define N_NODES   40000
#define N_EDGES   640000
#define F         128      // F_IN == HID == 128
#define N_GRAPHS  64
#define N_CLASSES 10

typedef short bf16x8 __attribute__((ext_vector_type(8)));
typedef float f32x4  __attribute__((ext_vector_type(4)));

// fp32 -> bf16 with round-to-nearest-even
__device__ __forceinline__ unsigned short f2bf(float f) {
    union { float f; unsigned u; } v; v.f = f;
    unsigned r = v.u + 0x7fffu + ((v.u >> 16) & 1u);
    return (unsigned short)(r >> 16);
}
__device__ __forceinline__ float bflo(unsigned u) { return __uint_as_float(u << 16); }
__device__ __forceinline__ float bfhi(unsigned u) { return __uint_as_float(u & 0xffff0000u); }
__device__ __forceinline__ unsigned pack2(float a, float b) {
    return (unsigned)f2bf(a) | ((unsigned)f2bf(b) << 16);
}

#define APITCH 136   // bf16 units; 272 B rows: 16B-aligned frags, bank-spread

// ---------------------------------------------------------------------------
// Precompute transposed bf16 weights: Wt_l[c][k] = bf16(W_l[k][c]), l=0..2.
// Fused: zero deg (for gemm1's degree count) and the scan ticket.
__global__ void wcvt_kernel(const float* __restrict__ W1, const float* __restrict__ W2,
                            const float* __restrict__ W3, unsigned short* __restrict__ Wt,
                            int* __restrict__ deg, int* __restrict__ tks) {
    int idx = blockIdx.x * 256 + threadIdx.x;          // 0 .. 3*16384-1
    if (idx < N_NODES) deg[idx] = 0;
    if (idx < 2) tks[idx] = 0;
    int l = idx >> 14;
    int r = idx & 16383;
    int c = r >> 7, k = r & 127;
    const float* W = (l == 0) ? W1 : ((l == 1) ? W2 : W3);
    Wt[idx] = f2bf(W[k * 128 + c]);                    // write coalesced (k fast)
}

// ---------------------------------------------------------------------------
// CSR scan v4 (validated R2): 40 blocks x 1000 nodes. Per-block sum ->
// chunkSum -> ticket spin -> wave-parallel scan of chunkSums. Also zeros
// pooled/cnt and computes dis[v] = rsqrt(deg[v]+1).
#define SCAN_BLOCKS 40
#define SCAN_CHUNK  1000
__global__ __launch_bounds__(256) void scan_kernel(
    const int* __restrict__ deg, int* __restrict__ rowptr,
    int* __restrict__ cursor, float* __restrict__ dis,
    float* __restrict__ pooled_zero, int* __restrict__ chunkSum,
    int* __restrict__ ticket) {
    __shared__ int wpart[4];
    __shared__ int blockBase;
    const int tid  = threadIdx.x;
    const int lane = tid & 63;
    const int wave = tid >> 6;
    const int b    = blockIdx.x;
    const int base = b * SCAN_CHUNK;

    for (int k = b * 256 + tid; k < N_GRAPHS * F + N_GRAPHS; k += SCAN_BLOCKS * 256)
        pooled_zero[k] = 0.f;

    int4 d = make_int4(0, 0, 0, 0);
    if (tid < 250) d = *(const int4*)(deg + base + tid * 4);
    const int sown = d.x + d.y + d.z + d.w;

    int s = sown;
#pragma unroll
    for (int off = 1; off < 64; off <<= 1) {
        int n = __shfl_up(s, off, 64);
        if (lane >= off) s += n;
    }
    if (lane == 63) wpart[wave] = s;
    __syncthreads();

    if (tid == 0) {
        int run = 0;
#pragma unroll
        for (int w = 0; w < 4; ++w) { int t = wpart[w]; wpart[w] = run; run += t; }
        atomicExch(&chunkSum[b], run);
        __threadfence();
        atomicAdd(ticket, 1);
        while (atomicAdd(ticket, 0) < SCAN_BLOCKS) { }
    }
    __syncthreads();

    // Wave 0: parallel exclusive scan of chunkSum[0..39] (atomic loads for
    // cross-XCD visibility; one round-trip instead of b serial ones).
    if (wave == 0) {
        int cs = (lane < SCAN_BLOCKS) ? atomicAdd(&chunkSum[lane], 0) : 0;
        int sc_ = cs;
#pragma unroll
        for (int off = 1; off < 64; off <<= 1) {
            int n = __shfl_up(sc_, off, 64);
            if (lane >= off) sc_ += n;
        }
        int bb = __shfl(sc_, (b == 0) ? 0 : b - 1, 64);
        if (lane == 0) blockBase = (b == 0) ? 0 : bb;
    }
    __syncthreads();

    if (tid < 250) {
        int excl = blockBase + wpart[wave] + (s - sown);
        int4 r;
        r.x = excl;
        r.y = r.x + d.x;
        r.z = r.y + d.y;
        r.w = r.z + d.z;
        *(int4*)(rowptr + base + tid * 4) = r;
        *(int4*)(cursor + base + tid * 4) = r;
        float4 di;
        di.x = rsqrtf((float)d.x + 1.0f);
        di.y = rsqrtf((float)d.y + 1.0f);
        di.z = rsqrtf((float)d.z + 1.0f);
        di.w = rsqrtf((float)d.w + 1.0f);
        *(float4*)(dis + base + tid * 4) = di;
    }
}

// CSR build step 3: csr_src[cursor[col[e]]++] = row[e]
__global__ void fill_kernel(const int* __restrict__ row, const int* __restrict__ col,
                            int* __restrict__ cursor, int* __restrict__ csr_src) {
    int e = blockIdx.x * 256 + threadIdx.x;
    if (e < N_EDGES) {
        int pos = atomicAdd(&cursor[col[e]], 1);
        csr_src[pos] = row[e];
    }
}

// ---------------------------------------------------------------------------
// MFMA GEMM v2 (validated): Hb[r][c] = bf16( scale_r * relu?(A[r][:] + bias) @ W )
// W^T staged in TWO 64-col halves: LDS = As 17KB + Ws-half 17KB = 34 KB
// -> 4 blocks/CU for cross-block latency hiding.
// Fragment maps (verified m89/m92/m120): A: m=lane&15, k=quad*8+j;
// B^T: n=lane&15, k=quad*8+j; D: col=lane&15, row=quad*4+reg.
// Epilogue: D -> As (wave-private rows, no barrier) -> coalesced uint4 stores.
template<bool ABF16, bool RELU, bool SCALE, bool COUNT>
__global__ __launch_bounds__(256) void gemm_mfma(
    const void* __restrict__ Araw, const unsigned short* __restrict__ Wt,
    const float* __restrict__ bias, const float* __restrict__ dis,
    unsigned short* __restrict__ Hb,
    const int* __restrict__ cnt_col, int* __restrict__ cnt_deg) {
    __shared__ unsigned short As[64 * APITCH];    // 17408 B
    __shared__ unsigned short Ws[64 * APITCH];    // 17408 B (one 64-col half)
    const int tid  = threadIdx.x;
    const int row0 = blockIdx.x * 64;

    if (COUNT) {   // fused degree count for CSR build (deg pre-zeroed)
        int t = (blockIdx.x * 256 + tid) * 4;
#pragma unroll
        for (int j = 0; j < 4; ++j) atomicAdd(&cnt_deg[cnt_col[t + j]], 1);
    }

    // Stage Ws half 0 (cols 0..63 of W^T; 1024 uint4)
    {
        const uint4* src = (const uint4*)Wt;
#pragma unroll
        for (int j = 0; j < 4; ++j) {
            int c4 = tid + j * 256;        // 0..1023; 16 uint4 per 128-bf16 row
            int c  = c4 >> 4;
            int o  = c4 & 15;
            *(uint4*)(Ws + c * APITCH + o * 8) = src[c4];
        }
    }
    // Stage A -> bias/relu -> bf16 -> As
    if (ABF16) {
        const uint4* src = (const uint4*)Araw;     // 16 uint4 per 128-bf16 row
#pragma unroll
        for (int j = 0; j < 4; ++j) {
            int c4 = tid + j * 256;        // 0..1023
            int r  = c4 >> 4;
            int p  = c4 & 15;
            int o  = p << 3;               // bf16 col offset (8 per chunk)
            uint4 hv = src[(size_t)(row0 + r) * 16 + p];
            float f0 = bflo(hv.x), f1 = bfhi(hv.x), f2 = bflo(hv.y), f3 = bfhi(hv.y);
            float f4_ = bflo(hv.z), f5 = bfhi(hv.z), f6 = bflo(hv.w), f7 = bfhi(hv.w);
            if (bias) {
                float4 b0 = *(const float4*)(bias + o);
                float4 b1 = *(const float4*)(bias + o + 4);
                f0 += b0.x; f1 += b0.y; f2 += b0.z; f3 += b0.w;
                f4_ += b1.x; f5 += b1.y; f6 += b1.z; f7 += b1.w;
            }
            if (RELU) {
                f0 = fmaxf(f0, 0.f); f1 = fmaxf(f1, 0.f); f2 = fmaxf(f2, 0.f);
                f3 = fmaxf(f3, 0.f); f4_ = fmaxf(f4_, 0.f); f5 = fmaxf(f5, 0.f);
                f6 = fmaxf(f6, 0.f); f7 = fmaxf(f7, 0.f);
            }
            uint4 pk;
            pk.x = pack2(f0, f1); pk.y = pack2(f2, f3);
            pk.z = pack2(f4_, f5); pk.w = pack2(f6, f7);
            *(uint4*)(As + r * APITCH + o) = pk;
        }
    } else {
        const float* A = (const float*)Araw;
#pragma unroll
        for (int j = 0; j < 8; ++j) {
            int c4 = tid + j * 256;            // 0..2047; 32 float4 per row
            int r  = c4 >> 5;
            int o  = (c4 & 31) << 2;
            float4 v = *(const float4*)(A + (size_t)(row0 + r) * F + o);
            if (bias) {
                v.x += bias[o + 0]; v.y += bias[o + 1];
                v.z += bias[o + 2]; v.w += bias[o + 3];
            }
            if (RELU) {
                v.x = fmaxf(v.x, 0.f); v.y = fmaxf(v.y, 0.f);
                v.z = fmaxf(v.z, 0.f); v.w = fmaxf(v.w, 0.f);
            }
            uint2 p;
            p.x = pack2(v.x, v.y);
            p.y = pack2(v.z, v.w);
            *(uint2*)(As + r * APITCH + o) = p;
        }
    }
    __syncthreads();

    const int lane = tid & 63;
    const int wave = tid >> 6;
    const int m16  = lane & 15;
    const int quad = lane >> 4;

    f32x4 acc[8];
#pragma unroll
    for (int t = 0; t < 8; ++t) acc[t] = (f32x4)(0.0f);

    // A fragments are reused across both halves — load once.
    bf16x8 afrag[4];
#pragma unroll
    for (int kk = 0; kk < 4; ++kk)
        afrag[kk] = *(const bf16x8*)(As + (wave * 16 + m16) * APITCH + kk * 32 + quad * 8);

    // --- half 0: output cols 0..63 (acc[0..3]) ---
#pragma unroll
    for (int kk = 0; kk < 4; ++kk) {
#pragma unroll
        for (int t = 0; t < 4; ++t) {
            bf16x8 b = *(const bf16x8*)(Ws + (t * 16 + m16) * APITCH + kk * 32 + quad * 8);
            acc[t] = __builtin_amdgcn_mfma_f32_16x16x32_bf16(afrag[kk], b, acc[t], 0, 0, 0);
        }
    }
    __syncthreads();   // all waves done reading Ws half 0

    // Stage Ws half 1 (cols 64..127)
    {
        const uint4* src = (const uint4*)Wt + 1024;
#pragma unroll
        for (int j = 0; j < 4; ++j) {
            int c4 = tid + j * 256;
            int c  = c4 >> 4;
            int o  = c4 & 15;
            *(uint4*)(Ws + c * APITCH + o * 8) = src[c4];
        }
    }
    __syncthreads();

    // --- half 1: output cols 64..127 (acc[4..7]) ---
#pragma unroll
    for (int kk = 0; kk < 4; ++kk) {
#pragma unroll
        for (int t = 0; t < 4; ++t) {
            bf16x8 b = *(const bf16x8*)(Ws + (t * 16 + m16) * APITCH + kk * 32 + quad * 8);
            acc[4 + t] = __builtin_amdgcn_mfma_f32_16x16x32_bf16(afrag[kk], b, acc[4 + t], 0, 0, 0);
        }
    }

    // Epilogue: D row = quad*4+reg, col = t*16+m16; optional dis[row] scale.
    // Stage into As rows (wave-private) -> read back -> coalesced stores.
    const int rloc = wave * 16 + quad * 4;
    float sc[4];
#pragma unroll
    for (int rg = 0; rg < 4; ++rg) sc[rg] = SCALE ? dis[row0 + rloc + rg] : 1.0f;
#pragma unroll
    for (int t = 0; t < 8; ++t) {
        int col = t * 16 + m16;
#pragma unroll
        for (int rg = 0; rg < 4; ++rg)
            As[(rloc + rg) * APITCH + col] = f2bf(acc[t][rg] * sc[rg]);
    }
#pragma unroll
    for (int i = 0; i < 4; ++i) {
        int idx = lane + i * 64;          // 0..255
        int r   = idx >> 4;               // 0..15
        int p   = idx & 15;               // 16B chunk
        uint4 val = *(const uint4*)(As + (wave * 16 + r) * APITCH + p * 8);
        *((uint4*)(Hb + (size_t)(row0 + wave * 16 + r) * F) + p) = val;
    }
}

// ---------------------------------------------------------------------------
// Gather aggregation v8: one wave per node; 16 edges per step, 4 independent
// uint4 gathers in flight per lane.  vs v5: edge indices are loaded DIRECTLY
// per lane (16-lane groups share an address -> HW broadcast), deleting the
// csr staging load + 4 ds_bpermute per step (one full LDS-latency dependent
// hop on the gather critical path).  Main loop is predication-free
// (len & ~15); tail iteration handles the remainder with w-masking.
// Per-lane edge order identical to v5 -> bit-identical accumulation.
// (v7 panel-split REGRESSED: duplicated per-edge VALU across 2 passes,
// VALUBusy 56%; v6 deep-ILP REGRESSED: occupancy loss.)
// SCALED=false: Hb pre-scaled by dis[row]:  AGG[v] = dis[v]*(sum Hb[src] + Hb[v])
// SCALED=true : AGG[v] = dis[v]*(sum dis[src]*Hb[src] + dis[v]*Hb[v])
template <bool SCALED>
__global__ __launch_bounds__(256) void gather_kernel(
    const unsigned short* __restrict__ Hb, const int* __restrict__ csr_src,
    const int* __restrict__ rowptr, const int* __restrict__ deg,
    const float* __restrict__ dis, unsigned short* __restrict__ AGGb) {
    const int gid  = blockIdx.x * 256 + threadIdx.x;
    const int v    = gid >> 6;
    if (v >= N_NODES) return;
    const int lane = threadIdx.x & 63;
    const int part = lane & 15;          // 16B chunk of the 256B row
    const int quad = lane >> 4;          // edge slot within group of 4

    const int start = rowptr[v];
    const int len   = deg[v];
    const uint4* Hp = (const uint4*)Hb + part;   // 16 uint4 per row

    float acc[8];
#pragma unroll
    for (int i = 0; i < 8; ++i) acc[i] = 0.f;

    const int jmain = len & ~15;
    for (int j = 0; j < jmain; j += 16) {        // full 16-edge blocks, no predication
        int   r[4];
        uint4 h[4];
#pragma unroll
        for (int u = 0; u < 4; ++u)
            r[u] = csr_src[start + j + u * 4 + quad];    // broadcast within part-group
#pragma unroll
        for (int u = 0; u < 4; ++u) h[u] = Hp[(size_t)r[u] * 16];
        float w[4];
#pragma unroll
        for (int u = 0; u < 4; ++u) w[u] = SCALED ? dis[r[u]] : 1.0f;
#pragma unroll
        for (int u = 0; u < 4; ++u) {
            acc[0] = fmaf(bflo(h[u].x), w[u], acc[0]);
            acc[1] = fmaf(bfhi(h[u].x), w[u], acc[1]);
            acc[2] = fmaf(bflo(h[u].y), w[u], acc[2]);
            acc[3] = fmaf(bfhi(h[u].y), w[u], acc[3]);
            acc[4] = fmaf(bflo(h[u].z), w[u], acc[4]);
            acc[5] = fmaf(bfhi(h[u].z), w[u], acc[5]);
            acc[6] = fmaf(bflo(h[u].w), w[u], acc[6]);
            acc[7] = fmaf(bfhi(h[u].w), w[u], acc[7]);
        }
    }
    if (jmain < len) {                           // tail (len >= 1 here)
        int   r[4];
        float w[4];
        uint4 h[4];
#pragma unroll
        for (int u = 0; u < 4; ++u) {
            int  sl    = jmain + u * 4 + quad;
            bool valid = sl < len;
            r[u] = csr_src[start + (valid ? sl : len - 1)];
            w[u] = valid ? (SCALED ? dis[r[u]] : 1.0f) : 0.0f;
        }
#pragma unroll
        for (int u = 0; u < 4; ++u) h[u] = Hp[(size_t)r[u] * 16];
#pragma unroll
        for (int u = 0; u < 4; ++u) {
            acc[0] = fmaf(bflo(h[u].x), w[u], acc[0]);
            acc[1] = fmaf(bfhi(h[u].x), w[u], acc[1]);
            acc[2] = fmaf(bflo(h[u].y), w[u], acc[2]);
            acc[3] = fmaf(bfhi(h[u].y), w[u], acc[3]);
            acc[4] = fmaf(bflo(h[u].z), w[u], acc[4]);
            acc[5] = fmaf(bfhi(h[u].z), w[u], acc[5]);
            acc[6] = fmaf(bflo(h[u].w), w[u], acc[6]);
            acc[7] = fmaf(bfhi(h[u].w), w[u], acc[7]);
        }
    }

#pragma unroll
    for (int i = 0; i < 8; ++i) {
        acc[i] += __shfl_xor(acc[i], 16, 64);
        acc[i] += __shfl_xor(acc[i], 32, 64);
    }

    if (quad == 0) {
        float dc  = dis[v];
        float ws_ = SCALED ? dc : 1.0f;
        uint4 h = Hp[(size_t)v * 16];               // self-loop
        acc[0] = fmaf(bflo(h.x), ws_, acc[0]); acc[1] = fmaf(bfhi(h.x), ws_, acc[1]);
        acc[2] = fmaf(bflo(h.y), ws_, acc[2]); acc[3] = fmaf(bfhi(h.y), ws_, acc[3]);
        acc[4] = fmaf(bflo(h.z), ws_, acc[4]); acc[5] = fmaf(bfhi(h.z), ws_, acc[5]);
        acc[6] = fmaf(bflo(h.w), ws_, acc[6]); acc[7] = fmaf(bfhi(h.w), ws_, acc[7]);
        uint4 pk;
        pk.x = pack2(acc[0] * dc, acc[1] * dc);
        pk.y = pack2(acc[2] * dc, acc[3] * dc);
        pk.z = pack2(acc[4] * dc, acc[5] * dc);
        pk.w = pack2(acc[6] * dc, acc[7] * dc);
        *((uint4*)AGGb + (size_t)v * 16 + part) = pk;
    }
}

// ---------------------------------------------------------------------------
// Pool v3 (validated): 400 blocks x 100 nodes; 8 row-slots x 32 lanes x 4 cols.
// pooled[g][f] += relu(AGG[v][f] + b3[f]); cnt[g] += 1. batch sorted ->
// per-slot run-length accumulate, flush on change.
#define POOL_NODES 100
__global__ __launch_bounds__(256) void pool_kernel(
    const unsigned short* __restrict__ AGGb, const int* __restrict__ batch,
    const float* __restrict__ b3,
    float* __restrict__ pooled, float* __restrict__ cnt) {
    const int tid  = threadIdx.x;
    const int f4   = (tid & 31) << 2;     // 4-col group
    const int slot = tid >> 5;            // 0..7
    const int base = blockIdx.x * POOL_NODES;
    const float4 bf = *(const float4*)(b3 + f4);

    float4 acc = make_float4(0.f, 0.f, 0.f, 0.f);
    float c = 0.f;
    int gcur = -1;
    for (int j = slot; j < POOL_NODES; j += 8) {
        int v = base + j;                 // 400*100 = 40000, always in range
        int g = batch[v];
        if (g != gcur) {
            if (gcur >= 0) {
                float* dst = pooled + gcur * F + f4;
                atomicAdd(dst + 0, acc.x); atomicAdd(dst + 1, acc.y);
                atomicAdd(dst + 2, acc.z); atomicAdd(dst + 3, acc.w);
                if (f4 == 0) atomicAdd(&cnt[gcur], c);
            }
            acc = make_float4(0.f, 0.f, 0.f, 0.f); c = 0.f; gcur = g;
        }
        uint2 a = *(const uint2*)(AGGb + (size_t)v * F + f4);
        acc.x += fmaxf(bflo(a.x) + bf.x, 0.f);
        acc.y += fmaxf(bfhi(a.x) + bf.y, 0.f);
        acc.z += fmaxf(bflo(a.y) + bf.z, 0.f);
        acc.w += fmaxf(bfhi(a.y) + bf.w, 0.f);
        c += 1.f;
    }
    if (gcur >= 0) {
        float* dst = pooled + gcur * F + f4;
        atomicAdd(dst + 0, acc.x); atomicAdd(dst + 1, acc.y);
        atomicAdd(dst + 2, acc.z); atomicAdd(dst + 3, acc.w);
        if (f4 == 0) atomicAdd(&cnt[gcur], c);
    }
}

// ---------------------------------------------------------------------------
// Head: out[g][c] = (sum_f pooled[g][f] * Wl[f][c]) / max(cnt[g],1) + bl[c]
__global__ void head_kernel(const float* __restrict__ pooled,
                            const float* __restrict__ cnt,
                            const float* __restrict__ Wl,
                            const float* __restrict__ bl,
                            float* __restrict__ out) {
    int tid = threadIdx.x;
    if (tid >= N_GRAPHS * N_CLASSES) return;
    int g = tid / N_CLASSES, c = tid % N_CLASSES;
    float acc = 0.f;
    for (int ff = 0; ff < F; ++ff)
        acc += pooled[g * F + ff] * Wl[ff * N_CLASSES + c];
    out[g * N_CLASSES + c] = acc / fmaxf(cnt[g], 1.f) + bl[c];
}

// ---------------------------------------------------------------------------
extern "C" void kernel_launch(void* const* d_in, const int* in_sizes, int n_in,
                              void* d_out, int out_size, void* d_ws, size_t ws_size,
                              hipStream_t stream) {
    const float* x    = (const float*)d_in[0];
    const int*   ei   = (const int*)d_in[1];     // [2][E]
    const int*   bat  = (const int*)d_in[2];
    const float* W1   = (const float*)d_in[3];
    const float* b1   = (const float*)d_in[4];
    const float* W2   = (const float*)d_in[5];
    const float* b2   = (const float*)d_in[6];
    const float* W3   = (const float*)d_in[7];
    const float* b3   = (const float*)d_in[8];
    const float* Wl   = (const float*)d_in[9];
    const float* bl   = (const float*)d_in[10];
    float* out = (float*)d_out;

    const int* row = ei;                 // edge_index[0] (source)
    const int* col = ei + N_EDGES;       // edge_index[1] (target)

    // Workspace layout (16B-aligned chunks)
    float*          ws      = (float*)d_ws;
    float*          dis     = ws;                                     // 40000 f
    unsigned short* Hb      = (unsigned short*)(dis + N_NODES);       // 5.12M bf16
    unsigned short* AGGb    = Hb + (size_t)N_NODES * F;               // 5.12M bf16
    float*          pooled  = (float*)(AGGb + (size_t)N_NODES * F);   // 8192 f
    float*          cnt     = pooled + N_GRAPHS * F;                  // 64 f
    int*            deg     = (int*)(cnt + N_GRAPHS);                 // 40000 i
    int*            rowptr  = deg + N_NODES;                          // 40000 i
    int*            cursor  = rowptr + N_NODES;                       // 40000 i
    int*            csr_src = cursor + N_NODES;                       // 640000 i
    unsigned short* Wtb     = (unsigned short*)(csr_src + N_EDGES);   // 3*16384 bf16
    int*            chunkSum= (int*)(Wtb + 3 * 16384);                // 40 i
    int*            tks     = chunkSum + SCAN_BLOCKS;                 // 2 i

    const int edgeGrid   = (N_EDGES + 255) / 256;      // 2500
    const int gemmGrid   = N_NODES / 64;               // 625
    const int gatherGrid = (N_NODES * 64) / 256;       // 10000

    // --- W convert + zero deg/ticket (one kernel) ---
    wcvt_kernel<<<192, 256, 0, stream>>>(W1, W2, W3, Wtb, deg, tks);

    // --- layer 1 GEMM (unscaled bf16 H, fused degree count), then CSR build ---
    gemm_mfma<false, false, false, true><<<gemmGrid, 256, 0, stream>>>(
        x, Wtb, nullptr, nullptr, Hb, col, deg);
    scan_kernel<<<SCAN_BLOCKS, 256, 0, stream>>>(deg, rowptr, cursor, dis,
                                                 pooled, chunkSum, &tks[0]);
    fill_kernel<<<edgeGrid, 256, 0, stream>>>(row, col, cursor, csr_src);
    gather_kernel<true><<<gatherGrid, 256, 0, stream>>>(Hb, csr_src, rowptr, deg, dis, AGGb);

    // --- layer 2 (relu(agg+b1) fused into staging; H pre-scaled by dis) ---
    gemm_mfma<true, true, true, false><<<gemmGrid, 256, 0, stream>>>(
        AGGb, Wtb + 16384, b1, dis, Hb, nullptr, nullptr);
    gather_kernel<false><<<gatherGrid, 256, 0, stream>>>(Hb, csr_src, rowptr, deg, dis, AGGb);

    // --- layer 3 ---
    gemm_mfma<true, true, true, false><<<gemmGrid, 256, 0, stream>>>(
        AGGb, Wtb + 32768, b2, dis, Hb, nullptr, nullptr);
    gather_kernel<false><<<gatherGrid, 256, 0, stream>>>(Hb, csr_src, rowptr, deg, dis, AGGb);

    // --- pool (fuses relu(agg + b3)) + head ---
    pool_kernel<<<N_NODES / POOL_NODES, 256, 0, stream>>>(AGGb, bat, b3, pooled, cnt);
    head_kernel<<<1, N_GRAPHS * N_CLASSES, 0, stream>>>(pooled, cnt, Wl, bl, out);
}

// Round 6
// 290.219 us; speedup vs baseline: 1.1426x; 1.0095x over previous
//
#include <hip/hip_runtime.h>
#include <hip/hip_bf16.h>

// Problem constants (from reference)
#define N_NODES   40000
#define N_EDGES   640000
#define F         128      // F_IN == HID == 128
#define N_GRAPHS  64
#define N_CLASSES 10

typedef short bf16x8 __attribute__((ext_vector_type(8)));
typedef float f32x4  __attribute__((ext_vector_type(4)));

// fp32 -> bf16 with round-to-nearest-even
__device__ __forceinline__ unsigned short f2bf(float f) {
    union { float f; unsigned u; } v; v.f = f;
    unsigned r = v.u + 0x7fffu + ((v.u >> 16) & 1u);
    return (unsigned short)(r >> 16);
}
__device__ __forceinline__ float bflo(unsigned u) { return __uint_as_float(u << 16); }
__device__ __forceinline__ float bfhi(unsigned u) { return __uint_as_float(u & 0xffff0000u); }
__device__ __forceinline__ unsigned pack2(float a, float b) {
    return (unsigned)f2bf(a) | ((unsigned)f2bf(b) << 16);
}

#define APITCH 136   // bf16 units; 272 B rows: 16B-aligned frags, bank-spread

// H / AGG live as TWO column panels [2][N][64] bf16 (5.12 MB each). Each
// gather PASS is a separate kernel launch touching one panel only, so the
// random-read working set (~5.6 MB incl csr) is L2/L3-resident instead of
// thrashing (v7 measured 45.5 MB HBM fetch = 9x refetch of a 5.12 MB panel
// because its two "phases" co-ran in one launch).
#define PANEL_U4  ((size_t)N_NODES * 8)     // panel stride in uint4 units

// ---------------------------------------------------------------------------
// Precompute transposed bf16 weights: Wt_l[c][k] = bf16(W_l[k][c]), l=0..2.
// Fused: zero deg (for gemm1's degree count) and the scan ticket.
__global__ void wcvt_kernel(const float* __restrict__ W1, const float* __restrict__ W2,
                            const float* __restrict__ W3, unsigned short* __restrict__ Wt,
                            int* __restrict__ deg, int* __restrict__ tks) {
    int idx = blockIdx.x * 256 + threadIdx.x;          // 0 .. 3*16384-1
    if (idx < N_NODES) deg[idx] = 0;
    if (idx < 2) tks[idx] = 0;
    int l = idx >> 14;
    int r = idx & 16383;
    int c = r >> 7, k = r & 127;
    const float* W = (l == 0) ? W1 : ((l == 1) ? W2 : W3);
    Wt[idx] = f2bf(W[k * 128 + c]);                    // write coalesced (k fast)
}

// ---------------------------------------------------------------------------
// CSR scan v4 (validated R2): 40 blocks x 1000 nodes. Per-block sum ->
// chunkSum -> ticket spin -> wave-parallel scan of chunkSums. Also zeros
// pooled/cnt and computes dis[v] = rsqrt(deg[v]+1).
#define SCAN_BLOCKS 40
#define SCAN_CHUNK  1000
__global__ __launch_bounds__(256) void scan_kernel(
    const int* __restrict__ deg, int* __restrict__ rowptr,
    int* __restrict__ cursor, float* __restrict__ dis,
    float* __restrict__ pooled_zero, int* __restrict__ chunkSum,
    int* __restrict__ ticket) {
    __shared__ int wpart[4];
    __shared__ int blockBase;
    const int tid  = threadIdx.x;
    const int lane = tid & 63;
    const int wave = tid >> 6;
    const int b    = blockIdx.x;
    const int base = b * SCAN_CHUNK;

    for (int k = b * 256 + tid; k < N_GRAPHS * F + N_GRAPHS; k += SCAN_BLOCKS * 256)
        pooled_zero[k] = 0.f;

    int4 d = make_int4(0, 0, 0, 0);
    if (tid < 250) d = *(const int4*)(deg + base + tid * 4);
    const int sown = d.x + d.y + d.z + d.w;

    int s = sown;
#pragma unroll
    for (int off = 1; off < 64; off <<= 1) {
        int n = __shfl_up(s, off, 64);
        if (lane >= off) s += n;
    }
    if (lane == 63) wpart[wave] = s;
    __syncthreads();

    if (tid == 0) {
        int run = 0;
#pragma unroll
        for (int w = 0; w < 4; ++w) { int t = wpart[w]; wpart[w] = run; run += t; }
        atomicExch(&chunkSum[b], run);
        __threadfence();
        atomicAdd(ticket, 1);
        while (atomicAdd(ticket, 0) < SCAN_BLOCKS) { }
    }
    __syncthreads();

    // Wave 0: parallel exclusive scan of chunkSum[0..39] (atomic loads for
    // cross-XCD visibility; one round-trip instead of b serial ones).
    if (wave == 0) {
        int cs = (lane < SCAN_BLOCKS) ? atomicAdd(&chunkSum[lane], 0) : 0;
        int sc_ = cs;
#pragma unroll
        for (int off = 1; off < 64; off <<= 1) {
            int n = __shfl_up(sc_, off, 64);
            if (lane >= off) sc_ += n;
        }
        int bb = __shfl(sc_, (b == 0) ? 0 : b - 1, 64);
        if (lane == 0) blockBase = (b == 0) ? 0 : bb;
    }
    __syncthreads();

    if (tid < 250) {
        int excl = blockBase + wpart[wave] + (s - sown);
        int4 r;
        r.x = excl;
        r.y = r.x + d.x;
        r.z = r.y + d.y;
        r.w = r.z + d.z;
        *(int4*)(rowptr + base + tid * 4) = r;
        *(int4*)(cursor + base + tid * 4) = r;
        float4 di;
        di.x = rsqrtf((float)d.x + 1.0f);
        di.y = rsqrtf((float)d.y + 1.0f);
        di.z = rsqrtf((float)d.z + 1.0f);
        di.w = rsqrtf((float)d.w + 1.0f);
        *(float4*)(dis + base + tid * 4) = di;
    }
}

// CSR build step 3: csr_src[cursor[col[e]]++] = row[e]
__global__ void fill_kernel(const int* __restrict__ row, const int* __restrict__ col,
                            int* __restrict__ cursor, int* __restrict__ csr_src) {
    int e = blockIdx.x * 256 + threadIdx.x;
    if (e < N_EDGES) {
        int pos = atomicAdd(&cursor[col[e]], 1);
        csr_src[pos] = row[e];
    }
}

// ---------------------------------------------------------------------------
// MFMA GEMM v3 (panel I/O, validated R4): Hb[r][c] = bf16(scale_r * relu?(A+b) @ W)
// A (bf16 case) read from panel layout [2][N][64]; D written to panel layout.
// W^T staged in TWO 64-col halves: LDS = As 17KB + Ws-half 17KB = 34 KB.
// Fragment maps (verified m89/m92/m120): A: m=lane&15, k=quad*8+j;
// B^T: n=lane&15, k=quad*8+j; D: col=lane&15, row=quad*4+reg.
template<bool ABF16, bool RELU, bool SCALE, bool COUNT>
__global__ __launch_bounds__(256) void gemm_mfma(
    const void* __restrict__ Araw, const unsigned short* __restrict__ Wt,
    const float* __restrict__ bias, const float* __restrict__ dis,
    unsigned short* __restrict__ Hb,
    const int* __restrict__ cnt_col, int* __restrict__ cnt_deg) {
    __shared__ unsigned short As[64 * APITCH];    // 17408 B
    __shared__ unsigned short Ws[64 * APITCH];    // 17408 B (one 64-col half)
    const int tid  = threadIdx.x;
    const int row0 = blockIdx.x * 64;

    if (COUNT) {   // fused degree count for CSR build (deg pre-zeroed)
        int t = (blockIdx.x * 256 + tid) * 4;
#pragma unroll
        for (int j = 0; j < 4; ++j) atomicAdd(&cnt_deg[cnt_col[t + j]], 1);
    }

    // Stage Ws half 0 (cols 0..63 of W^T; 1024 uint4)
    {
        const uint4* src = (const uint4*)Wt;
#pragma unroll
        for (int j = 0; j < 4; ++j) {
            int c4 = tid + j * 256;        // 0..1023; 16 uint4 per 128-bf16 row
            int c  = c4 >> 4;
            int o  = c4 & 15;
            *(uint4*)(Ws + c * APITCH + o * 8) = src[c4];
        }
    }
    // Stage A -> bias/relu -> bf16 -> As
    if (ABF16) {
        const uint4* src = (const uint4*)Araw;     // panel layout [2][N][64]
#pragma unroll
        for (int j = 0; j < 4; ++j) {
            int c4 = tid + j * 256;        // 0..1023
            int r  = c4 >> 4;
            int p  = c4 & 15;
            int o  = p << 3;               // bf16 col offset (8 per chunk)
            uint4 hv = src[(size_t)(p >> 3) * PANEL_U4 + (size_t)(row0 + r) * 8 + (p & 7)];
            float f0 = bflo(hv.x), f1 = bfhi(hv.x), f2 = bflo(hv.y), f3 = bfhi(hv.y);
            float f4_ = bflo(hv.z), f5 = bfhi(hv.z), f6 = bflo(hv.w), f7 = bfhi(hv.w);
            if (bias) {
                float4 b0 = *(const float4*)(bias + o);
                float4 b1 = *(const float4*)(bias + o + 4);
                f0 += b0.x; f1 += b0.y; f2 += b0.z; f3 += b0.w;
                f4_ += b1.x; f5 += b1.y; f6 += b1.z; f7 += b1.w;
            }
            if (RELU) {
                f0 = fmaxf(f0, 0.f); f1 = fmaxf(f1, 0.f); f2 = fmaxf(f2, 0.f);
                f3 = fmaxf(f3, 0.f); f4_ = fmaxf(f4_, 0.f); f5 = fmaxf(f5, 0.f);
                f6 = fmaxf(f6, 0.f); f7 = fmaxf(f7, 0.f);
            }
            uint4 pk;
            pk.x = pack2(f0, f1); pk.y = pack2(f2, f3);
            pk.z = pack2(f4_, f5); pk.w = pack2(f6, f7);
            *(uint4*)(As + r * APITCH + o) = pk;
        }
    } else {
        const float* A = (const float*)Araw;   // x: row-major [N][128] fp32
#pragma unroll
        for (int j = 0; j < 8; ++j) {
            int c4 = tid + j * 256;            // 0..2047; 32 float4 per row
            int r  = c4 >> 5;
            int o  = (c4 & 31) << 2;
            float4 v = *(const float4*)(A + (size_t)(row0 + r) * F + o);
            if (bias) {
                v.x += bias[o + 0]; v.y += bias[o + 1];
                v.z += bias[o + 2]; v.w += bias[o + 3];
            }
            if (RELU) {
                v.x = fmaxf(v.x, 0.f); v.y = fmaxf(v.y, 0.f);
                v.z = fmaxf(v.z, 0.f); v.w = fmaxf(v.w, 0.f);
            }
            uint2 p;
            p.x = pack2(v.x, v.y);
            p.y = pack2(v.z, v.w);
            *(uint2*)(As + r * APITCH + o) = p;
        }
    }
    __syncthreads();

    const int lane = tid & 63;
    const int wave = tid >> 6;
    const int m16  = lane & 15;
    const int quad = lane >> 4;

    f32x4 acc[8];
#pragma unroll
    for (int t = 0; t < 8; ++t) acc[t] = (f32x4)(0.0f);

    // A fragments are reused across both halves — load once.
    bf16x8 afrag[4];
#pragma unroll
    for (int kk = 0; kk < 4; ++kk)
        afrag[kk] = *(const bf16x8*)(As + (wave * 16 + m16) * APITCH + kk * 32 + quad * 8);

    // --- half 0: output cols 0..63 (acc[0..3]) ---
#pragma unroll
    for (int kk = 0; kk < 4; ++kk) {
#pragma unroll
        for (int t = 0; t < 4; ++t) {
            bf16x8 b = *(const bf16x8*)(Ws + (t * 16 + m16) * APITCH + kk * 32 + quad * 8);
            acc[t] = __builtin_amdgcn_mfma_f32_16x16x32_bf16(afrag[kk], b, acc[t], 0, 0, 0);
        }
    }
    __syncthreads();   // all waves done reading Ws half 0

    // Stage Ws half 1 (cols 64..127)
    {
        const uint4* src = (const uint4*)Wt + 1024;
#pragma unroll
        for (int j = 0; j < 4; ++j) {
            int c4 = tid + j * 256;
            int c  = c4 >> 4;
            int o  = c4 & 15;
            *(uint4*)(Ws + c * APITCH + o * 8) = src[c4];
        }
    }
    __syncthreads();

    // --- half 1: output cols 64..127 (acc[4..7]) ---
#pragma unroll
    for (int kk = 0; kk < 4; ++kk) {
#pragma unroll
        for (int t = 0; t < 4; ++t) {
            bf16x8 b = *(const bf16x8*)(Ws + (t * 16 + m16) * APITCH + kk * 32 + quad * 8);
            acc[4 + t] = __builtin_amdgcn_mfma_f32_16x16x32_bf16(afrag[kk], b, acc[4 + t], 0, 0, 0);
        }
    }

    // Epilogue: D row = quad*4+reg, col = t*16+m16; optional dis[row] scale.
    // Stage into As rows (wave-private) -> read back -> coalesced panel stores.
    const int rloc = wave * 16 + quad * 4;
    float sc[4];
#pragma unroll
    for (int rg = 0; rg < 4; ++rg) sc[rg] = SCALE ? dis[row0 + rloc + rg] : 1.0f;
#pragma unroll
    for (int t = 0; t < 8; ++t) {
        int col = t * 16 + m16;
#pragma unroll
        for (int rg = 0; rg < 4; ++rg)
            As[(rloc + rg) * APITCH + col] = f2bf(acc[t][rg] * sc[rg]);
    }
#pragma unroll
    for (int i = 0; i < 4; ++i) {
        int idx = lane + i * 64;          // 0..255
        int r   = idx >> 4;               // 0..15
        int p   = idx & 15;               // 16B chunk; panel = p>>3
        uint4 val = *(const uint4*)(As + (wave * 16 + r) * APITCH + p * 8);
        *((uint4*)Hb + (size_t)(p >> 3) * PANEL_U4
                     + (size_t)(row0 + wave * 16 + r) * 8 + (p & 7)) = val;
    }
}

// ---------------------------------------------------------------------------
// Gather aggregation v9: 8-LANE GROUP PER NODE, one PANEL per LAUNCH.
// Each launch (pass = 0 or 1, separate kernels -> hard barrier) reads only
// one 5.12 MB panel randomly -> L2/L3 resident, ~compulsory HBM fetch.
// Group of 8 lanes x 16B covers the full 128B panel row; the group
// accumulates its node's edges sequentially, 4 at a time (4 independent
// uint4 gathers in flight) -> NO shuffle reduction, NO divergent epilogue,
// 8 nodes per wave amortize setup (v5/v8 spent ~half the kernel on per-node
// reduction+epilogue at avg degree 16).  Per-instruction memory shape is
// unchanged: 64 lanes = 8 random 128B segments.
// SCALED=false: Hb pre-scaled by dis[row]:  AGG[v] = dis[v]*(sum Hb[src] + Hb[v])
// SCALED=true : AGG[v] = dis[v]*(sum dis[src]*Hb[src] + dis[v]*Hb[v])
template <bool SCALED>
__global__ __launch_bounds__(256) void gather_kernel(
    const unsigned short* __restrict__ Hb, const int* __restrict__ csr_src,
    const int* __restrict__ rowptr, const int* __restrict__ deg,
    const float* __restrict__ dis, unsigned short* __restrict__ AGGb,
    int pass) {
    const int grp  = threadIdx.x >> 3;              // 0..31
    const int v    = blockIdx.x * 32 + grp;         // 1250*32 = 40000 exact
    const int c8   = threadIdx.x & 7;               // 16B chunk of 128B row

    const int start = rowptr[v];
    const int len   = deg[v];
    const uint4* Hp   = (const uint4*)Hb + (size_t)pass * PANEL_U4 + c8;
    uint4*       AGGp = (uint4*)AGGb + (size_t)pass * PANEL_U4 + c8;

    float acc[8];
#pragma unroll
    for (int i = 0; i < 8; ++i) acc[i] = 0.f;

    const int jmain = len & ~3;
    int j = 0;
    for (; j < jmain; j += 4) {          // 4 edges per step, no predication
        int   r[4];
        uint4 h[4];
        float w[4];
#pragma unroll
        for (int u = 0; u < 4; ++u) r[u] = csr_src[start + j + u];   // group-broadcast
#pragma unroll
        for (int u = 0; u < 4; ++u) h[u] = Hp[(size_t)r[u] * 8];
#pragma unroll
        for (int u = 0; u < 4; ++u) w[u] = SCALED ? dis[r[u]] : 1.0f;
#pragma unroll
        for (int u = 0; u < 4; ++u) {
            acc[0] = fmaf(bflo(h[u].x), w[u], acc[0]);
            acc[1] = fmaf(bfhi(h[u].x), w[u], acc[1]);
            acc[2] = fmaf(bflo(h[u].y), w[u], acc[2]);
            acc[3] = fmaf(bfhi(h[u].y), w[u], acc[3]);
            acc[4] = fmaf(bflo(h[u].z), w[u], acc[4]);
            acc[5] = fmaf(bfhi(h[u].z), w[u], acc[5]);
            acc[6] = fmaf(bflo(h[u].w), w[u], acc[6]);
            acc[7] = fmaf(bfhi(h[u].w), w[u], acc[7]);
        }
    }
    if (j < len) {                       // tail 1..3 edges (len >= 1 here)
        int   r[4];
        uint4 h[4];
        float w[4];
#pragma unroll
        for (int u = 0; u < 4; ++u) {
            int  sl    = j + u;
            bool valid = sl < len;
            r[u] = csr_src[start + (valid ? sl : len - 1)];
            w[u] = valid ? (SCALED ? dis[r[u]] : 1.0f) : 0.0f;
        }
#pragma unroll
        for (int u = 0; u < 4; ++u) h[u] = Hp[(size_t)r[u] * 8];
#pragma unroll
        for (int u = 0; u < 4; ++u) {
            acc[0] = fmaf(bflo(h[u].x), w[u], acc[0]);
            acc[1] = fmaf(bfhi(h[u].x), w[u], acc[1]);
            acc[2] = fmaf(bflo(h[u].y), w[u], acc[2]);
            acc[3] = fmaf(bfhi(h[u].y), w[u], acc[3]);
            acc[4] = fmaf(bflo(h[u].z), w[u], acc[4]);
            acc[5] = fmaf(bfhi(h[u].z), w[u], acc[5]);
            acc[6] = fmaf(bflo(h[u].w), w[u], acc[6]);
            acc[7] = fmaf(bfhi(h[u].w), w[u], acc[7]);
        }
    }

    // Epilogue: all 8 lanes of the group (no reduction, no divergence).
    {
        float dc  = dis[v];
        float ws_ = SCALED ? dc : 1.0f;
        uint4 h = Hp[(size_t)v * 8];               // self-loop
        acc[0] = fmaf(bflo(h.x), ws_, acc[0]); acc[1] = fmaf(bfhi(h.x), ws_, acc[1]);
        acc[2] = fmaf(bflo(h.y), ws_, acc[2]); acc[3] = fmaf(bfhi(h.y), ws_, acc[3]);
        acc[4] = fmaf(bflo(h.z), ws_, acc[4]); acc[5] = fmaf(bfhi(h.z), ws_, acc[5]);
        acc[6] = fmaf(bflo(h.w), ws_, acc[6]); acc[7] = fmaf(bfhi(h.w), ws_, acc[7]);
        uint4 pk;
        pk.x = pack2(acc[0] * dc, acc[1] * dc);
        pk.y = pack2(acc[2] * dc, acc[3] * dc);
        pk.z = pack2(acc[4] * dc, acc[5] * dc);
        pk.w = pack2(acc[6] * dc, acc[7] * dc);
        AGGp[(size_t)v * 8] = pk;
    }
}

// ---------------------------------------------------------------------------
// Pool v4 (panel reads, validated R4): 400 blocks x 100 nodes; 8 row-slots x
// 32 lanes x 4 cols. pooled[g][f] += relu(AGG[v][f] + b3[f]); cnt[g] += 1.
// batch sorted -> per-slot run-length accumulate, flush on change.
#define POOL_NODES 100
__global__ __launch_bounds__(256) void pool_kernel(
    const unsigned short* __restrict__ AGGb, const int* __restrict__ batch,
    const float* __restrict__ b3,
    float* __restrict__ pooled, float* __restrict__ cnt) {
    const int tid  = threadIdx.x;
    const int f4   = (tid & 31) << 2;     // 4-col group (0..124)
    const int slot = tid >> 5;            // 0..7
    const int base = blockIdx.x * POOL_NODES;
    const float4 bf = *(const float4*)(b3 + f4);
    const unsigned short* Ap = AGGb + (size_t)(f4 >> 6) * N_NODES * 64 + (f4 & 63);

    float4 acc = make_float4(0.f, 0.f, 0.f, 0.f);
    float c = 0.f;
    int gcur = -1;
    for (int j = slot; j < POOL_NODES; j += 8) {
        int v = base + j;                 // 400*100 = 40000, always in range
        int g = batch[v];
        if (g != gcur) {
            if (gcur >= 0) {
                float* dst = pooled + gcur * F + f4;
                atomicAdd(dst + 0, acc.x); atomicAdd(dst + 1, acc.y);
                atomicAdd(dst + 2, acc.z); atomicAdd(dst + 3, acc.w);
                if (f4 == 0) atomicAdd(&cnt[gcur], c);
            }
            acc = make_float4(0.f, 0.f, 0.f, 0.f); c = 0.f; gcur = g;
        }
        uint2 a = *(const uint2*)(Ap + (size_t)v * 64);
        acc.x += fmaxf(bflo(a.x) + bf.x, 0.f);
        acc.y += fmaxf(bfhi(a.x) + bf.y, 0.f);
        acc.z += fmaxf(bflo(a.y) + bf.z, 0.f);
        acc.w += fmaxf(bfhi(a.y) + bf.w, 0.f);
        c += 1.f;
    }
    if (gcur >= 0) {
        float* dst = pooled + gcur * F + f4;
        atomicAdd(dst + 0, acc.x); atomicAdd(dst + 1, acc.y);
        atomicAdd(dst + 2, acc.z); atomicAdd(dst + 3, acc.w);
        if (f4 == 0) atomicAdd(&cnt[gcur], c);
    }
}

// ---------------------------------------------------------------------------
// Head: out[g][c] = (sum_f pooled[g][f] * Wl[f][c]) / max(cnt[g],1) + bl[c]
__global__ void head_kernel(const float* __restrict__ pooled,
                            const float* __restrict__ cnt,
                            const float* __restrict__ Wl,
                            const float* __restrict__ bl,
                            float* __restrict__ out) {
    int tid = threadIdx.x;
    if (tid >= N_GRAPHS * N_CLASSES) return;
    int g = tid / N_CLASSES, c = tid % N_CLASSES;
    float acc = 0.f;
    for (int ff = 0; ff < F; ++ff)
        acc += pooled[g * F + ff] * Wl[ff * N_CLASSES + c];
    out[g * N_CLASSES + c] = acc / fmaxf(cnt[g], 1.f) + bl[c];
}

// ---------------------------------------------------------------------------
extern "C" void kernel_launch(void* const* d_in, const int* in_sizes, int n_in,
                              void* d_out, int out_size, void* d_ws, size_t ws_size,
                              hipStream_t stream) {
    const float* x    = (const float*)d_in[0];
    const int*   ei   = (const int*)d_in[1];     // [2][E]
    const int*   bat  = (const int*)d_in[2];
    const float* W1   = (const float*)d_in[3];
    const float* b1   = (const float*)d_in[4];
    const float* W2   = (const float*)d_in[5];
    const float* b2   = (const float*)d_in[6];
    const float* W3   = (const float*)d_in[7];
    const float* b3   = (const float*)d_in[8];
    const float* Wl   = (const float*)d_in[9];
    const float* bl   = (const float*)d_in[10];
    float* out = (float*)d_out;

    const int* row = ei;                 // edge_index[0] (source)
    const int* col = ei + N_EDGES;       // edge_index[1] (target)

    // Workspace layout (16B-aligned chunks)
    float*          ws      = (float*)d_ws;
    float*          dis     = ws;                                     // 40000 f
    unsigned short* Hb      = (unsigned short*)(dis + N_NODES);       // 5.12M bf16 (2 panels)
    unsigned short* AGGb    = Hb + (size_t)N_NODES * F;               // 5.12M bf16 (2 panels)
    float*          pooled  = (float*)(AGGb + (size_t)N_NODES * F);   // 8192 f
    float*          cnt     = pooled + N_GRAPHS * F;                  // 64 f
    int*            deg     = (int*)(cnt + N_GRAPHS);                 // 40000 i
    int*            rowptr  = deg + N_NODES;                          // 40000 i
    int*            cursor  = rowptr + N_NODES;                       // 40000 i
    int*            csr_src = cursor + N_NODES;                       // 640000 i
    unsigned short* Wtb     = (unsigned short*)(csr_src + N_EDGES);   // 3*16384 bf16
    int*            chunkSum= (int*)(Wtb + 3 * 16384);                // 40 i
    int*            tks     = chunkSum + SCAN_BLOCKS;                 // 2 i

    const int edgeGrid   = (N_EDGES + 255) / 256;      // 2500
    const int gemmGrid   = N_NODES / 64;               // 625
    const int gatherGrid = N_NODES / 32;               // 1250 (8-lane groups)

    // --- W convert + zero deg/ticket (one kernel) ---
    wcvt_kernel<<<192, 256, 0, stream>>>(W1, W2, W3, Wtb, deg, tks);

    // --- layer 1 GEMM (unscaled bf16 H, fused degree count), then CSR build ---
    gemm_mfma<false, false, false, true><<<gemmGrid, 256, 0, stream>>>(
        x, Wtb, nullptr, nullptr, Hb, col, deg);
    scan_kernel<<<SCAN_BLOCKS, 256, 0, stream>>>(deg, rowptr, cursor, dis,
                                                 pooled, chunkSum, &tks[0]);
    fill_kernel<<<edgeGrid, 256, 0, stream>>>(row, col, cursor, csr_src);
    gather_kernel<true><<<gatherGrid, 256, 0, stream>>>(Hb, csr_src, rowptr, deg, dis, AGGb, 0);
    gather_kernel<true><<<gatherGrid, 256, 0, stream>>>(Hb, csr_src, rowptr, deg, dis, AGGb, 1);

    // --- layer 2 (relu(agg+b1) fused into staging; H pre-scaled by dis) ---
    gemm_mfma<true, true, true, false><<<gemmGrid, 256, 0, stream>>>(
        AGGb, Wtb + 16384, b1, dis, Hb, nullptr, nullptr);
    gather_kernel<false><<<gatherGrid, 256, 0, stream>>>(Hb, csr_src, rowptr, deg, dis, AGGb, 0);
    gather_kernel<false><<<gatherGrid, 256, 0, stream>>>(Hb, csr_src, rowptr, deg, dis, AGGb, 1);

    // --- layer 3 ---
    gemm_mfma<true, true, true, false><<<gemmGrid, 256, 0, stream>>>(
        AGGb, Wtb + 32768, b2, dis, Hb, nullptr, nullptr);
    gather_kernel<false><<<gatherGrid, 256, 0, stream>>>(Hb, csr_src, rowptr, deg, dis, AGGb, 0);
    gather_kernel<false><<<gatherGrid, 256, 0, stream>>>(Hb, csr_src, rowptr, deg, dis, AGGb, 1);

    // --- pool (fuses relu(agg + b3)) + head ---
    pool_kernel<<<N_NODES / POOL_NODES, 256, 0, stream>>>(AGGb, bat, b3, pooled, cnt);
    head_kernel<<<1, N_GRAPHS * N_CLASSES, 0, stream>>>(pooled, cnt, Wl, bl, out);
}